// Round 7
// baseline (71.108 us; speedup 1.0000x reference)
//
#include <hip/hip_runtime.h>
#include <hip/hip_bf16.h>
#include <math.h>

// Problem constants
#define NB 8
#define LN 4096       // sequence length L
#define NH 8
#define NE 64
#define NC 512        // NH*NE channels
#define NM 64         // modes kept
#define LMASK 4095

typedef short s16x8 __attribute__((ext_vector_type(8)));
typedef float f32x4 __attribute__((ext_vector_type(4)));

// ws layout (in floats):
//  egf : bf16[128kc][8mt][64][8]        @ 0        (1 MB)  fwd twiddle A-fragments
//  tf  : bf16[4kk][256lt][64][8]        @ 262144   (1 MB)  inv twiddle B-fragments
//  gf  : bf16[8b][4kk][32ct][64][8]     @ 524288   (1 MB)  mixed-spectrum A-fragments
//  xs  : f32[8b][8h][64i][128m±]        @ 786432   (2 MB)  final spectrum
#define WS_EGF 0
#define WS_TF  262144
#define WS_GF  524288
#define WS_XS  786432

static __device__ __forceinline__ unsigned short bf16bits(float f) {
    __hip_bfloat16 b = __float2bfloat16(f);
    return *reinterpret_cast<unsigned short*>(&b);
}

// Both twiddle tables in one launch. Blocks 0..255: egf (fwd A-frags);
// blocks 256..511: tf (inv B-frags).
__global__ __launch_bounds__(256) void k_tables(unsigned short* __restrict__ egf,
                                                unsigned short* __restrict__ tfp) {
    const int bid = blockIdx.x;
    const int s = (bid & 255) * 256 + threadIdx.x;   // 0..65535
    const int lane = s & 63;
    unsigned short v[8];
    if (bid < 256) {
        // E[2m][l]=cos, E[2m+1][l]=-sin ; slot s=(kc<<9)|(mt<<6)|lane
        int mt = (s >> 6) & 7, kc = s >> 9;
        int r = lane & 15, kg = lane >> 4;
        int mpm = mt * 16 + r;
        int m = mpm >> 1, isim = mpm & 1;
        #pragma unroll
        for (int j = 0; j < 8; ++j) {
            int l = kc * 32 + kg * 8 + j;
            int tw = (m * l) & LMASK;
            float ang = (6.283185307179586f / 4096.0f) * (float)tw;
            v[j] = bf16bits(isim ? -sinf(ang) : cosf(ang));
        }
    } else {
        // T[l][2m]=cos, T[l][2m+1]=sin ; slot s=(kk<<14)|(lt<<6)|lane
        int lt = (s >> 6) & 255, kk = s >> 14;
        int l = lt * 16 + (lane & 15);
        int khi = (lane >> 4) * 8;
        #pragma unroll
        for (int j = 0; j < 8; ++j) {
            int mp = kk * 32 + khi + j;
            int m = mp >> 1;
            int tw = (m * l) & LMASK;
            float ang = (6.283185307179586f / 4096.0f) * (float)tw;
            v[j] = bf16bits((mp & 1) ? sinf(ang) : cosf(ang));
        }
    }
    uint4 pk;
    pk.x = (unsigned)v[0] | ((unsigned)v[1] << 16);
    pk.y = (unsigned)v[2] | ((unsigned)v[3] << 16);
    pk.z = (unsigned)v[4] | ((unsigned)v[5] << 16);
    pk.w = (unsigned)v[6] | ((unsigned)v[7] << 16);
    unsigned short* dst = (bid < 256) ? egf : tfp;
    *reinterpret_cast<uint4*>(dst + (size_t)s * 8) = pk;
}

// Fused stage 1 (v3): full K per block, final xs written directly (no presum).
// grid 256 blocks (XCD-swizzled), block 512 = 8 waves.
//   sid -> x = sid&7 (XCD), idx = sid>>3; p = x*8 + (idx&7) -> (b,h); mq = idx>>3.
//   4 mq-partner blocks share the same (b,h) q-slice and land on one XCD -> L2 reuse.
// Wave w8: w = w8&3 -> i-subtile [w*16,+16); ks = w8>>2 -> l-half [ks*2048,+2048).
// Each wave: 64 iters x (8 q dwords + 2 egf frags + 2 MFMA), m± slice [mq*32,+32).
// End: half ks=0 stores acc to LDS, barrier, half ks=1 adds and writes xs.
__global__ __launch_bounds__(512, 2) void k_fs1(const float* __restrict__ q,
                                                const unsigned short* __restrict__ egf,
                                                float* __restrict__ xs) {
    __shared__ float red[64 * 36];       // [i-local 64][m±-local 32 + 4 pad] = 9 KB
    const int sid = blockIdx.x;
    const int x   = sid & 7;
    const int idx = sid >> 3;
    const int p   = x * 8 + (idx & 7);   // (b,h) index 0..63
    const int mq  = idx >> 3;            // 0..3 -> m± base mq*32
    const int b = p >> 3, h = p & 7;
    const int tid = threadIdx.x;
    const int w8 = tid >> 6, lane = tid & 63;
    const int w  = w8 & 3;               // i-subtile
    const int ks = w8 >> 2;              // K-half
    const int i  = w * 16 + (lane & 15);
    const int lrow = (lane >> 4) * 8;

    // q[b][ks*2048 + t*32 + lrow + j][h][i]
    const float* qb = q + (((size_t)b * LN + ks * 2048 + lrow) * NH + h) * NE + i;
    // egf slot ((kc*8 + mt)*64 + lane)*8 ; kc = ks*64 + t ; mt = mq*2 + {0,1}
    const unsigned short* eb = egf + (((size_t)(ks * 64) * 8 + mq * 2) * 64 + lane) * 8;

    f32x4 acc[2] = {};
    float qv[2][8];
    s16x8 af[2][2];

#define FS1_LOAD(T, S)                                                            \
    {                                                                             \
        const float* qp_ = qb + (size_t)(T) * 32 * NC;                            \
        _Pragma("unroll")                                                         \
        for (int j = 0; j < 8; ++j) qv[S][j] = qp_[(size_t)j * NC];               \
        const unsigned short* ep_ = eb + (size_t)(T) * (8 * 64 * 8);              \
        af[S][0] = *reinterpret_cast<const s16x8*>(ep_);                          \
        af[S][1] = *reinterpret_cast<const s16x8*>(ep_ + 512);                    \
    }

#define FS1_STEP(T, CUR)                                                          \
    {                                                                             \
        if ((T) + 1 < 64) FS1_LOAD((T) + 1, 1 - (CUR))                            \
        s16x8 bfr;                                                                \
        _Pragma("unroll")                                                         \
        for (int j = 0; j < 8; ++j) bfr[j] = (short)bf16bits(qv[CUR][j]);         \
        acc[0] = __builtin_amdgcn_mfma_f32_16x16x32_bf16(af[CUR][0], bfr, acc[0], 0, 0, 0); \
        acc[1] = __builtin_amdgcn_mfma_f32_16x16x32_bf16(af[CUR][1], bfr, acc[1], 0, 0, 0); \
    }

    FS1_LOAD(0, 0)
    for (int tt = 0; tt < 32; ++tt) {
        FS1_STEP(2 * tt, 0)
        FS1_STEP(2 * tt + 1, 1)
    }
#undef FS1_STEP
#undef FS1_LOAD

    // Merge the two K-halves. D row = m±-local = (lane>>4)*4 + reg, col = i-local.
    const int r4 = (lane >> 4) * 4;
    const int il = w * 16 + (lane & 15);
    if (ks == 0) {
        #pragma unroll
        for (int mi = 0; mi < 2; ++mi)
            *reinterpret_cast<f32x4*>(&red[il * 36 + mi * 16 + r4]) = acc[mi];
    }
    __syncthreads();
    if (ks == 1) {
        float* xsb = xs + ((size_t)(b * 8 + h) * 64 + il) * 128 + mq * 32 + r4;
        #pragma unroll
        for (int mi = 0; mi < 2; ++mi) {
            f32x4 o = acc[mi] + *reinterpret_cast<const f32x4*>(&red[il * 36 + mi * 16 + r4]);
            *reinterpret_cast<f32x4*>(xsb + mi * 16) = o;
        }
    }
}

// Stage 2 (v3): channel mix, gf written directly (no part/s2red). grid 256 blocks
// (XCD-swizzled), block 256. sid -> x = sid&7, idx = sid>>3; r = x*8 + (idx&7)
// -> og = r>>3, h = r&7; bb = idx>>3 -> b in {bb*2, bb*2+1}. The 4 bb-partner
// blocks share the same w1/w2 slice on one XCD -> w read once from HBM.
// Block stages xs[2b][h][64i][64m] (64 KB) to LDS, then o-loop runs from LDS.
__global__ __launch_bounds__(256) void k_s2(const float* __restrict__ w1,
                                            const float* __restrict__ w2,
                                            const float* __restrict__ xs,
                                            unsigned short* __restrict__ gf) {
    __shared__ float2 sxs[2][64][64];    // [bsub][i][m] = 64 KB
    const int sid = blockIdx.x;
    const int x   = sid & 7;
    const int idx = sid >> 3;
    const int r   = x * 8 + (idx & 7);   // (og,h) index
    const int og  = r >> 3, h = r & 7;
    const int bb  = idx >> 3;            // 0..3
    const int tt  = threadIdx.x;

    {
        float4* dst = reinterpret_cast<float4*>(&sxs[0][0][0]);
        #pragma unroll
        for (int bs = 0; bs < 2; ++bs) {
            const float4* s4 = reinterpret_cast<const float4*>(
                xs + ((size_t)((bb * 2 + bs) * 8 + h)) * 8192);
            #pragma unroll
            for (int k = 0; k < 8; ++k)
                dst[bs * 2048 + k * 256 + tt] = s4[k * 256 + tt];
        }
    }
    __syncthreads();

    const int m    = tt & 63;
    const int osub = tt >> 6;            // 0..3
    const int o0   = og * 8 + osub * 2;  // 2 o per thread

    float re[2][2], im[2][2];            // [oo][bs]
    #pragma unroll
    for (int oo = 0; oo < 2; ++oo)
        #pragma unroll
        for (int bs = 0; bs < 2; ++bs) { re[oo][bs] = 0.f; im[oo][bs] = 0.f; }

    const float* w1p = w1 + (size_t)h * (NE * NE * NM) + (size_t)o0 * NM + m;
    const float* w2p = w2 + (size_t)h * (NE * NE * NM) + (size_t)o0 * NM + m;

    #pragma unroll 2
    for (int i = 0; i < NE; ++i) {
        float wr0 = w1p[(size_t)i * (NE * NM)];
        float wi0 = w2p[(size_t)i * (NE * NM)];
        float wr1 = w1p[(size_t)i * (NE * NM) + NM];
        float wi1 = w2p[(size_t)i * (NE * NM) + NM];
        #pragma unroll
        for (int bs = 0; bs < 2; ++bs) {
            float2 xv = sxs[bs][i][m];
            re[0][bs] = fmaf(xv.x, wr0, fmaf(-xv.y, wi0, re[0][bs]));
            im[0][bs] = fmaf(xv.x, wi0, fmaf( xv.y, wr0, im[0][bs]));
            re[1][bs] = fmaf(xv.x, wr1, fmaf(-xv.y, wi1, re[1][bs]));
            im[1][bs] = fmaf(xv.x, wi1, fmaf( xv.y, wr1, im[1][bs]));
        }
    }

    const float sca = (m == 0 ? 1.0f : 2.0f) / (float)LN;  // (2-delta_m0)/L fold
    // G[2m][c]=s*re, G[2m+1][c]=-s*im into A-fragment layout:
    // slot = ((b*4 + (m>>4))*32 + (c>>4))*64 + ((m&15)>>2)*16 + (c&15), elems ((m&3)<<1)+{0,1}
    const int kk  = m >> 4;
    const int khi = ((m & 15) >> 2) * 16;
    const int jj  = (m & 3) << 1;
    #pragma unroll
    for (int oo = 0; oo < 2; ++oo) {
        const int c = h * 64 + o0 + oo;
        #pragma unroll
        for (int bs = 0; bs < 2; ++bs) {
            const int b = bb * 2 + bs;
            size_t slot = (((size_t)b * 4 + kk) * 32 + (c >> 4)) * 64 + khi + (c & 15);
            unsigned int pk = (unsigned)bf16bits(re[oo][bs] * sca) |
                              ((unsigned)bf16bits(-im[oo][bs] * sca) << 16);
            *reinterpret_cast<unsigned int*>(gf + slot * 8 + jj) = pk;
        }
    }
}

// Stage 3 MFMA: per b: out[l][c] = sum_mp T[l][mp] * G[mp][c].  M=c(128/block), N=l(64/block), K=128.
// grid (64 lb, 4 cb, 8 b), block 256 = 4 waves; wave w owns c-quarter [w*32, w*32+32).
// Zero LDS / zero barriers; both operand tables stream from L2.
__global__ __launch_bounds__(256, 2) void k_s3(const unsigned short* __restrict__ gf,
                                               const unsigned short* __restrict__ tfp,
                                               float* __restrict__ out) {
    const int lb = blockIdx.x;   // l base = lb*64
    const int cb = blockIdx.y;   // c base = cb*128
    const int b  = blockIdx.z;
    const int tid = threadIdx.x;
    const int w = tid >> 6, lane = tid & 63;

    const unsigned short* ga = gf + ((((size_t)b * 4) * 32 + cb * 8 + w * 2) * 64 + lane) * 8;
    const unsigned short* tb = tfp + (((size_t)lb * 4) * 64 + lane) * 8;

    f32x4 acc[2][4] = {};
    s16x8 af[3][2], bf[3][4];

#define S3_LOAD(T, SLOT)                                                          \
    {                                                                             \
        const unsigned short* gp_ = ga + (size_t)(T) * (32 * 64 * 8);             \
        const unsigned short* tp_ = tb + (size_t)(T) * (256 * 64 * 8);            \
        af[SLOT][0] = *reinterpret_cast<const s16x8*>(gp_);                       \
        af[SLOT][1] = *reinterpret_cast<const s16x8*>(gp_ + 64 * 8);              \
        bf[SLOT][0] = *reinterpret_cast<const s16x8*>(tp_);                       \
        bf[SLOT][1] = *reinterpret_cast<const s16x8*>(tp_ + 64 * 8);              \
        bf[SLOT][2] = *reinterpret_cast<const s16x8*>(tp_ + 2 * 64 * 8);          \
        bf[SLOT][3] = *reinterpret_cast<const s16x8*>(tp_ + 3 * 64 * 8);          \
    }

    S3_LOAD(0, 0)
    S3_LOAD(1, 1)

    #pragma unroll
    for (int t = 0; t < 4; ++t) {
        const int slot = t % 3;
        if (t + 2 < 4) { const int ns = (t + 2) % 3; S3_LOAD(t + 2, ns) }
        #pragma unroll
        for (int mi = 0; mi < 2; ++mi)
            #pragma unroll
            for (int ni = 0; ni < 4; ++ni)
                acc[mi][ni] = __builtin_amdgcn_mfma_f32_16x16x32_bf16(
                    af[slot][mi], bf[slot][ni], acc[mi][ni], 0, 0, 0);
    }
#undef S3_LOAD

    // D[row=c_local][col=l_local]; f32x4 regs span 4 consecutive c.
    const int c0 = cb * 128 + w * 32 + (lane >> 4) * 4;
    const int l0 = lb * 64 + (lane & 15);
    #pragma unroll
    for (int mi = 0; mi < 2; ++mi)
        #pragma unroll
        for (int ni = 0; ni < 4; ++ni) {
            float* op = out + ((size_t)b * LN + l0 + ni * 16) * NC + c0 + mi * 16;
            *reinterpret_cast<f32x4*>(op) = acc[mi][ni];
        }
}

extern "C" void kernel_launch(void* const* d_in, const int* in_sizes, int n_in,
                              void* d_out, int out_size, void* d_ws, size_t ws_size,
                              hipStream_t stream) {
    const float* q  = (const float*)d_in[0];
    // d_in[1] (k) and d_in[2] (v) are unused by the reference
    const float* w1 = (const float*)d_in[3];
    const float* w2 = (const float*)d_in[4];
    float* out = (float*)d_out;
    float* ws  = (float*)d_ws;

    unsigned short* egf = (unsigned short*)(ws + WS_EGF);
    unsigned short* tfp = (unsigned short*)(ws + WS_TF);
    unsigned short* gf  = (unsigned short*)(ws + WS_GF);
    float*          xs  = ws + WS_XS;

    k_tables<<<512, 256, 0, stream>>>(egf, tfp);
    k_fs1<<<256, 512, 0, stream>>>(q, egf, xs);
    k_s2<<<256, 256, 0, stream>>>(w1, w2, xs, gf);
    k_s3<<<dim3(64, 4, NB), 256, 0, stream>>>(gf, tfp, out);
}